// Round 2
// baseline (137884.460 us; speedup 1.0000x reference)
//
#include <hip/hip_runtime.h>
#include <hip/hip_cooperative_groups.h>
#include <math.h>

namespace cg = cooperative_groups;

#define B_   64
#define U_   1024
#define E_   512
#define D_   640
#define L4_  2560
#define NWG  256

__device__ __forceinline__ float sigm(float x) { return 1.f / (1.f + __expf(-x)); }

// ---------------------------------------------------------------------------
// Weight prep: W0t[d][g][k] = U0[k][g*640+d]            (640x4x640)
//              Wc1[d][g][k] = (k<640 ? W1[k] : U1[k-640])[g*640+d]  (640x4x1280)
// ---------------------------------------------------------------------------
__global__ __launch_bounds__(256) void prep_weights(
    const float* __restrict__ U0, const float* __restrict__ W1,
    const float* __restrict__ U1, float* __restrict__ W0t,
    float* __restrict__ Wc1)
{
    size_t i = (size_t)blockIdx.x * blockDim.x + threadIdx.x;
    if (i < (size_t)640 * 4 * 640) {
        int k = (int)(i % 640); int g = (int)((i / 640) % 4); int d = (int)(i / 2560);
        W0t[i] = U0[(size_t)k * L4_ + g * 640 + d];
    }
    if (i < (size_t)640 * 4 * 1280) {
        int k = (int)(i % 1280); int g = (int)((i / 1280) % 4); int d = (int)(i / 5120);
        float v = (k < 640) ? W1[(size_t)k * L4_ + g * 640 + d]
                            : U1[(size_t)(k - 640) * L4_ + g * 640 + d];
        Wc1[i] = v;
    }
}

// ---------------------------------------------------------------------------
// GEMM: xz[tl][n][b] = b0[n] + sum_k embed[targets[b][t0+tl]][k] * W0[k][n]
// Block tile 128x128, 256 threads, 8x8 per-thread tile, BK=8.
// ---------------------------------------------------------------------------
__global__ __launch_bounds__(256) void gemm_kernel(
    const float* __restrict__ A, const int* __restrict__ targets,
    const float* __restrict__ Wm, const float* __restrict__ bias,
    float* __restrict__ xz, int K, int t0)
{
    const int tid = threadIdx.x;
    const int m0 = blockIdx.x * 128;
    const int n0 = blockIdx.y * 128;

    __shared__ float As[8][132];
    __shared__ float Bs[8][132];

    float acc[8][8];
#pragma unroll
    for (int i = 0; i < 8; ++i)
#pragma unroll
        for (int j = 0; j < 8; ++j) acc[i][j] = 0.f;

    const int a_ml = tid & 127;
    const int a_kq = (tid >> 7) * 4;
    {
        int m = m0 + a_ml;
        int b = m & 63;
        int tl = m >> 6;
        int idx = targets[b * U_ + t0 + tl];
        A += (size_t)idx * E_ + a_kq;
    }
    const int b_k  = tid >> 5;
    const int b_n4 = (tid & 31) * 4;
    const int tx = tid & 15;
    const int ty = tid >> 4;

    for (int k0 = 0; k0 < K; k0 += 8) {
        float4 av = *(const float4*)(A + k0);
        As[a_kq + 0][a_ml] = av.x;
        As[a_kq + 1][a_ml] = av.y;
        As[a_kq + 2][a_ml] = av.z;
        As[a_kq + 3][a_ml] = av.w;
        float4 bv = *(const float4*)(Wm + (size_t)(k0 + b_k) * L4_ + n0 + b_n4);
        *(float4*)&Bs[b_k][b_n4] = bv;
        __syncthreads();

#pragma unroll
        for (int k = 0; k < 8; ++k) {
            float af[8], bf[8];
            *(float4*)&af[0] = *(const float4*)&As[k][ty * 8];
            *(float4*)&af[4] = *(const float4*)&As[k][ty * 8 + 4];
            *(float4*)&bf[0] = *(const float4*)&Bs[k][tx * 8];
            *(float4*)&bf[4] = *(const float4*)&Bs[k][tx * 8 + 4];
#pragma unroll
            for (int i = 0; i < 8; ++i)
#pragma unroll
                for (int j = 0; j < 8; ++j) acc[i][j] += af[i] * bf[j];
        }
        __syncthreads();
    }

#pragma unroll
    for (int i = 0; i < 8; ++i) {
        int m  = m0 + ty * 8 + i;
        int tl = m >> 6;
        int b  = m & 63;
        float* outp = xz + (size_t)tl * (L4_ * 64) + b;
#pragma unroll
        for (int j = 0; j < 8; ++j) {
            int n = n0 + tx * 8 + j;
            outp[(size_t)n * 64] = acc[i][j] + bias[n];
        }
    }
}

// ---------------------------------------------------------------------------
// Accumulate ND d-columns x 4 gates over [k0, k0+KCNT) of hsrc (layout [k][b]).
// Weight base pointers wb[dd] point at Wt + d*4*KSTRIDE; gate stride KSTRIDE.
// ---------------------------------------------------------------------------
template <int ND, int KSTRIDE, int KCNT>
__device__ __forceinline__ void accum_dot(
    const float* __restrict__ hsrc, const float* const (&wb)[3],
    int k0, int b, float (&acc)[3][4])
{
#pragma unroll 4
    for (int j = 0; j < KCNT; ++j) {
        int k = k0 + j;
        float hv = hsrc[(size_t)k * 64 + b];
#pragma unroll
        for (int dd = 0; dd < ND; ++dd) {
            const float* wp = wb[dd] + k;
#pragma unroll
            for (int g = 0; g < 4; ++g)
                acc[dd][g] = fmaf(hv, wp[(size_t)g * KSTRIDE], acc[dd][g]);
        }
    }
}

// ---------------------------------------------------------------------------
// Persistent cooperative recurrence over one chunk of TCi steps.
// Layer 0 at iteration i computes global step tA = t0+i (i < TCi).
// Layer 1 at iteration i computes global step tB = t0+i-1 (i > 0).
// One grid.sync per iteration. Ping-pong h buffers indexed by step parity.
// WG w owns layer0 d in {w, w+256, w+512}∩[0,640),
//          layer1 d in {255-w, 511-w, 767-w}∩[0,640).
// ---------------------------------------------------------------------------
__global__ __launch_bounds__(256) void recur_kernel(
    const float* __restrict__ xz,     // [TC][2560][64]
    const float* __restrict__ W0t,    // [640][4][640]
    const float* __restrict__ Wc1,    // [640][4][1280]
    const float* __restrict__ b1,     // [2560]
    const int*   __restrict__ lens,   // [64]
    float* __restrict__ h0buf,        // [2][640*64]
    float* __restrict__ h1buf,        // [2][640*64]
    float* __restrict__ c0g,          // [640*64]
    float* __restrict__ c1g,          // [640*64]
    float* __restrict__ h1c,          // [TC][640][64]
    int t0, int TCi)
{
    cg::grid_group grid = cg::this_grid();
    const int w   = blockIdx.x;
    const int tid = threadIdx.x;
    const int b   = tid & 63;
    const int ks  = tid >> 6;          // 0..3 (also didx for finalize)

    int d0[3]; int nd0 = 0;
#pragma unroll
    for (int j = 0; j < 3; ++j) { int d = w + 256 * j; if (d < 640) d0[nd0++] = d; }
    const int v = 255 - w;
    int d1[3]; int nd1 = 0;
#pragma unroll
    for (int j = 0; j < 3; ++j) { int d = v + 256 * j; if (d < 640) d1[nd1++] = d; }

    const float* wb0[3] = { W0t, W0t, W0t };
    for (int j = 0; j < nd0; ++j) wb0[j] = W0t + (size_t)d0[j] * 2560;
    const float* wb1[3] = { Wc1, Wc1, Wc1 };
    for (int j = 0; j < nd1; ++j) wb1[j] = Wc1 + (size_t)d1[j] * 5120;

    __shared__ float red0[3][4][4][64];
    __shared__ float red1[3][4][4][64];

    // Persistent per-thread state: thread (ks, b) owns layer0 d0[ks], layer1 d1[ks].
    const int len_b = lens[b];
    float c0r = 0.f, h0r = 0.f, c1r = 0.f, h1r = 0.f;
    if (ks < nd0) {
        c0r = c0g[d0[ks] * 64 + b];
        h0r = h0buf[(size_t)((t0 + 1) & 1) * 40960 + d0[ks] * 64 + b];
    }
    if (ks < nd1) {
        c1r = c1g[d1[ks] * 64 + b];
        h1r = h1buf[(size_t)((t0 + 1) & 1) * 40960 + d1[ks] * 64 + b];
    }

    for (int i = 0; i <= TCi; ++i) {
        const int tA = t0 + i;
        const int tB = t0 + i - 1;

        float a0[3][4] = {};
        float a1[3][4] = {};

        if (i < TCi) {
            const float* h0p = h0buf + (size_t)((tA + 1) & 1) * 40960;
            if (nd0 == 3) accum_dot<3, 640, 160>(h0p, wb0, ks * 160, b, a0);
            else          accum_dot<2, 640, 160>(h0p, wb0, ks * 160, b, a0);
        }
        if (i > 0) {
            const float* hsB;
            if (ks < 2) hsB = h0buf + (size_t)(tB & 1) * 40960;
            else        hsB = h1buf + (size_t)((tB + 1) & 1) * 40960 - (size_t)640 * 64;
            if (nd1 == 3) accum_dot<3, 1280, 320>(hsB, wb1, ks * 320, b, a1);
            else          accum_dot<2, 1280, 320>(hsB, wb1, ks * 320, b, a1);
        }

        // stash partials
#pragma unroll
        for (int dd = 0; dd < 3; ++dd)
#pragma unroll
            for (int g = 0; g < 4; ++g) {
                red0[dd][g][ks][b] = a0[dd][g];
                red1[dd][g][ks][b] = a1[dd][g];
            }
        __syncthreads();

        // finalize layer 0
        if (i < TCi && ks < nd0) {
            const int d = d0[ks];
            float z[4];
#pragma unroll
            for (int g = 0; g < 4; ++g) {
                float s = red0[ks][g][0][b] + red0[ks][g][1][b]
                        + red0[ks][g][2][b] + red0[ks][g][3][b];
                z[g] = s + xz[((size_t)i * L4_ + g * 640 + d) * 64 + b];
            }
            float ig = sigm(z[0]), fg = sigm(z[1]);
            float gg = tanhf(z[2]), og = sigm(z[3]);
            float cn = fg * c0r + ig * gg;
            float hn = og * tanhf(cn);
            bool m = (tA < len_b);
            h0r = m ? hn : h0r;
            c0r = m ? cn : c0r;
            h0buf[(size_t)(tA & 1) * 40960 + d * 64 + b] = h0r;
            if (i == TCi - 1) c0g[d * 64 + b] = c0r;
        }
        // finalize layer 1
        if (i > 0 && ks < nd1) {
            const int d = d1[ks];
            float z[4];
#pragma unroll
            for (int g = 0; g < 4; ++g) {
                float s = red1[ks][g][0][b] + red1[ks][g][1][b]
                        + red1[ks][g][2][b] + red1[ks][g][3][b];
                z[g] = s + b1[g * 640 + d];
            }
            float ig = sigm(z[0]), fg = sigm(z[1]);
            float gg = tanhf(z[2]), og = sigm(z[3]);
            float cn = fg * c1r + ig * gg;
            float hn = og * tanhf(cn);
            bool m = (tB < len_b);
            h1r = m ? hn : h1r;
            c1r = m ? cn : c1r;
            h1buf[(size_t)(tB & 1) * 40960 + d * 64 + b] = h1r;
            h1c[((size_t)(i - 1) * D_ + d) * 64 + b] = h1r;
            if (i == TCi) c1g[d * 64 + b] = c1r;
        }
        grid.sync();
    }
}

// ---------------------------------------------------------------------------
// Transpose chunk h1c [tl][d][b] -> out [b][t0+tl][d]
// ---------------------------------------------------------------------------
__global__ __launch_bounds__(256) void transpose_kernel(
    const float* __restrict__ h1c, float* __restrict__ out, int t0)
{
    const int tl   = blockIdx.x;
    const int dblk = blockIdx.y;
    __shared__ float tile[64][65];

    const int r  = threadIdx.x >> 2;
    const int cq = threadIdx.x & 3;

    const float* src = h1c + (size_t)tl * (D_ * 64) + (size_t)(dblk * 64 + r) * 64 + cq * 16;
#pragma unroll
    for (int j = 0; j < 4; ++j) {
        float4 vv = *(const float4*)(src + j * 4);
        tile[r][cq * 16 + j * 4 + 0] = vv.x;
        tile[r][cq * 16 + j * 4 + 1] = vv.y;
        tile[r][cq * 16 + j * 4 + 2] = vv.z;
        tile[r][cq * 16 + j * 4 + 3] = vv.w;
    }
    __syncthreads();

    float* dst = out + (size_t)r * (U_ * D_) + (size_t)(t0 + tl) * D_ + dblk * 64 + cq * 16;
#pragma unroll
    for (int j = 0; j < 4; ++j) {
        float4 ww;
        ww.x = tile[cq * 16 + j * 4 + 0][r];
        ww.y = tile[cq * 16 + j * 4 + 1][r];
        ww.z = tile[cq * 16 + j * 4 + 2][r];
        ww.w = tile[cq * 16 + j * 4 + 3][r];
        *(float4*)(dst + j * 4) = ww;
    }
}

// ---------------------------------------------------------------------------
extern "C" void kernel_launch(void* const* d_in, const int* in_sizes, int n_in,
                              void* d_out, int out_size, void* d_ws, size_t ws_size,
                              hipStream_t stream)
{
    const int*   targets = (const int*)d_in[0];
    const int*   lens    = (const int*)d_in[1];
    const float* embed   = (const float*)d_in[2];
    const float* W0      = (const float*)d_in[3];
    const float* U0      = (const float*)d_in[4];
    const float* b0      = (const float*)d_in[5];
    const float* W1      = (const float*)d_in[6];
    const float* U1      = (const float*)d_in[7];
    const float* b1      = (const float*)d_in[8];
    float* out = (float*)d_out;
    float* ws  = (float*)d_ws;

    // pick chunk size by workspace budget
    // bytes(TC) = 4*(TC*204800 + 5,160,960)
    const int TC  = (ws_size >= (size_t)73072640) ? 64 : 32;
    const int NCH = U_ / TC;

    float* xz    = ws;                                    // TC*2560*64
    float* h1c   = xz  + (size_t)TC * L4_ * 64;           // TC*640*64
    float* W0t   = h1c + (size_t)TC * D_ * 64;            // 1,638,400
    float* Wc1   = W0t + (size_t)640 * 4 * 640;           // 3,276,800
    float* st    = Wc1 + (size_t)640 * 4 * 1280;
    float* h0buf = st;                                    // 2*40960
    float* h1buf = st + 2 * 40960;                        // 2*40960
    float* c0g   = st + 4 * 40960;
    float* c1g   = st + 5 * 40960;

    hipMemsetAsync(st, 0, (size_t)6 * 40960 * sizeof(float), stream);

    prep_weights<<<dim3(12800), dim3(256), 0, stream>>>(U0, W1, U1, W0t, Wc1);

    const dim3 blk(256);
    for (int ch = 0; ch < NCH; ++ch) {
        int t0 = ch * TC;

        gemm_kernel<<<dim3(TC * 64 / 128, L4_ / 128), blk, 0, stream>>>(
            embed, targets, W0, b0, xz, E_, t0);

        int t0v = t0, TCv = TC;
        void* args[] = { (void*)&xz, (void*)&W0t, (void*)&Wc1, (void*)&b1,
                         (void*)&lens, (void*)&h0buf, (void*)&h1buf,
                         (void*)&c0g, (void*)&c1g, (void*)&h1c,
                         (void*)&t0v, (void*)&TCv };
        hipLaunchCooperativeKernel((void*)recur_kernel, dim3(NWG), blk, args, 0, stream);

        transpose_kernel<<<dim3(TC, 10), blk, 0, stream>>>(h1c, out, t0);
    }
}

// Round 4
// 73285.730 us; speedup vs baseline: 1.8815x; 1.8815x over previous
//
#include <hip/hip_runtime.h>
#include <hip/hip_cooperative_groups.h>
#include <math.h>

namespace cg = cooperative_groups;

#define B_   64
#define U_   1024
#define E_   512
#define D_   640
#define L4_  2560
#define SLOT 40960           // 640*64 floats per h slot
#define RWG  480             // recurrence WGs: 160 layer-0 + 320 layer-1

__device__ __forceinline__ float sigm(float x) { return 1.f / (1.f + __expf(-x)); }

// ---------------------------------------------------------------------------
// Weight prep (gate-interleaved, contiguous-k layouts):
//   W0t[d][k][g] = U0[k][g*640+d]                         (640 x 640 x 4)
//   Wc1[d][k][g] = (k<640 ? W1[k] : U1[k-640])[g*640+d]   (640 x 1280 x 4)
// ---------------------------------------------------------------------------
__global__ __launch_bounds__(256) void prep_weights(
    const float* __restrict__ U0, const float* __restrict__ W1,
    const float* __restrict__ U1, float* __restrict__ W0t,
    float* __restrict__ Wc1)
{
    int idx = blockIdx.x * 256 + threadIdx.x;
    if (idx < 640 * 640) {
        int d = idx / 640, k = idx % 640;
        const float* src = U0 + (size_t)k * L4_;
        float4 v;
        v.x = src[d]; v.y = src[640 + d]; v.z = src[1280 + d]; v.w = src[1920 + d];
        *(float4*)(W0t + (size_t)idx * 4) = v;
    }
    if (idx < 640 * 1280) {
        int d = idx / 1280, k = idx % 1280;
        const float* src = (k < 640) ? (W1 + (size_t)k * L4_)
                                     : (U1 + (size_t)(k - 640) * L4_);
        float4 v;
        v.x = src[d]; v.y = src[640 + d]; v.z = src[1280 + d]; v.w = src[1920 + d];
        *(float4*)(Wc1 + (size_t)idx * 4) = v;
    }
}

// ---------------------------------------------------------------------------
// GEMM0: xz[tl][n][b] = b0[n] + sum_k embed[targets[b][t0+tl]][k] * W0[k][n]
// Block tile 128x128, 256 threads, 8x8 per-thread tile, BK=8.
// ---------------------------------------------------------------------------
__global__ __launch_bounds__(256) void gemm_kernel(
    const float* __restrict__ A, const int* __restrict__ targets,
    const float* __restrict__ Wm, const float* __restrict__ bias,
    float* __restrict__ xz, int t0)
{
    const int tid = threadIdx.x;
    const int m0 = blockIdx.x * 128;
    const int n0 = blockIdx.y * 128;

    __shared__ float As[8][132];
    __shared__ float Bs[8][132];

    float acc[8][8];
#pragma unroll
    for (int i = 0; i < 8; ++i)
#pragma unroll
        for (int j = 0; j < 8; ++j) acc[i][j] = 0.f;

    const int a_ml = tid & 127;
    const int a_kq = (tid >> 7) * 4;
    {
        int m = m0 + a_ml;
        int b = m & 63;
        int tl = m >> 6;
        int idx = targets[b * U_ + t0 + tl];
        A += (size_t)idx * E_ + a_kq;
    }
    const int b_k  = tid >> 5;
    const int b_n4 = (tid & 31) * 4;
    const int tx = tid & 15;
    const int ty = tid >> 4;

    for (int k0 = 0; k0 < E_; k0 += 8) {
        float4 av = *(const float4*)(A + k0);
        As[a_kq + 0][a_ml] = av.x;
        As[a_kq + 1][a_ml] = av.y;
        As[a_kq + 2][a_ml] = av.z;
        As[a_kq + 3][a_ml] = av.w;
        float4 bv = *(const float4*)(Wm + (size_t)(k0 + b_k) * L4_ + n0 + b_n4);
        *(float4*)&Bs[b_k][b_n4] = bv;
        __syncthreads();

#pragma unroll
        for (int k = 0; k < 8; ++k) {
            float af[8], bf[8];
            *(float4*)&af[0] = *(const float4*)&As[k][ty * 8];
            *(float4*)&af[4] = *(const float4*)&As[k][ty * 8 + 4];
            *(float4*)&bf[0] = *(const float4*)&Bs[k][tx * 8];
            *(float4*)&bf[4] = *(const float4*)&Bs[k][tx * 8 + 4];
#pragma unroll
            for (int i = 0; i < 8; ++i)
#pragma unroll
                for (int j = 0; j < 8; ++j) acc[i][j] += af[i] * bf[j];
        }
        __syncthreads();
    }

#pragma unroll
    for (int i = 0; i < 8; ++i) {
        int m  = m0 + ty * 8 + i;
        int tl = m >> 6;
        int b  = m & 63;
        float* outp = xz + (size_t)tl * (L4_ * 64) + b;
#pragma unroll
        for (int j = 0; j < 8; ++j) {
            int n = n0 + tx * 8 + j;
            outp[(size_t)n * 64] = acc[i][j] + bias[n];
        }
    }
}

// ---------------------------------------------------------------------------
// Cooperative per-chunk recurrence. 480 WGs x 512 threads, one grid.sync per
// step. History slots: h0s/h1s have TCc+1 slots; slot s (s in [1,TCc]) holds
// h[t0+s-1]; slot TCc doubles as carry-in "h[t0-1]" (written by the previous
// chunk, read only at iters 0/1, overwritten only at iters TCc-1/TCc).
// Slots are written exactly once per chunk -> no WAR hazards anywhere.
//   WGs [0,160):   layer 0, 4 d's each; iter i computes t = t0+i   (i < TCc)
//   WGs [160,480): layer 1, 2 d's each; iter i computes t = t0+i-1 (i > 0)
// Layer-1 K=1280: k<640 -> h0[t] (W1 part), k>=640 -> h1[t-1] (U1 part).
// c/h state for each (d,b) lives in its owner thread's registers all chunk.
// ---------------------------------------------------------------------------
__global__ __launch_bounds__(512) void recur_chunk(
    const float* __restrict__ xz,     // [TCc][2560][64]
    const float* __restrict__ W0t,    // [640][640][4]
    const float* __restrict__ Wc1,    // [640][1280][4]
    const float* __restrict__ b1,     // [2560]
    const int*   __restrict__ lens,   // [64]
    float* __restrict__ h0s,          // [TCc+1][640][64]
    float* __restrict__ h1s,          // [TCc+1][640][64]
    float* __restrict__ c0g,          // [640*64]
    float* __restrict__ c1g,          // [640*64]
    int t0, int TCc)
{
    cg::grid_group grid = cg::this_grid();
    __shared__ float red[4][4][8][64];   // [didx][gate][wave][b] 32 KiB
    const int wg  = blockIdx.x;
    const int tid = threadIdx.x;
    const int b   = tid & 63;
    const int wv  = __builtin_amdgcn_readfirstlane(tid >> 6);  // wave 0..7
    const int len_b = lens[b];

    if (wg < 160) {
        // ----------------------------- layer 0 -----------------------------
        const int d0   = wg * 4;
        const int didx = tid >> 6;            // owners: tid < 256
        const int od   = d0 + (didx & 3);
        float c_r = 0.f, h_r = 0.f;
        if (tid < 256) {
            c_r = c0g[od * 64 + b];
            h_r = h0s[(size_t)SLOT * TCc + od * 64 + b];
        }
        const float* wbase = W0t + (size_t)d0 * 2560;
        const int k0 = wv * 80;

        for (int i = 0; i <= TCc; ++i) {
            if (i < TCc) {
                const float* hsrc = h0s + (size_t)SLOT * (i == 0 ? TCc : i);
                float acc[4][4] = {};
#pragma unroll 4
                for (int j = 0; j < 80; ++j) {
                    const int k = k0 + j;
                    const float hv = hsrc[k * 64 + b];
#pragma unroll
                    for (int dd = 0; dd < 4; ++dd) {
                        const float4 w4 = *(const float4*)(wbase + (size_t)dd * 2560 + (size_t)k * 4);
                        acc[dd][0] = fmaf(hv, w4.x, acc[dd][0]);
                        acc[dd][1] = fmaf(hv, w4.y, acc[dd][1]);
                        acc[dd][2] = fmaf(hv, w4.z, acc[dd][2]);
                        acc[dd][3] = fmaf(hv, w4.w, acc[dd][3]);
                    }
                }
#pragma unroll
                for (int dd = 0; dd < 4; ++dd)
#pragma unroll
                    for (int g = 0; g < 4; ++g) red[dd][g][wv][b] = acc[dd][g];
                __syncthreads();
                if (tid < 256) {
                    float z[4];
#pragma unroll
                    for (int g = 0; g < 4; ++g) {
                        float s = 0.f;
#pragma unroll
                        for (int w2 = 0; w2 < 8; ++w2) s += red[didx][g][w2][b];
                        z[g] = s + xz[((size_t)i * L4_ + g * 640 + od) * 64 + b];
                    }
                    float ig = sigm(z[0]), fg = sigm(z[1]);
                    float gg = tanhf(z[2]), og = sigm(z[3]);
                    float cn = fg * c_r + ig * gg;
                    float hn = og * tanhf(cn);
                    bool  m  = (t0 + i) < len_b;
                    h_r = m ? hn : h_r;
                    c_r = m ? cn : c_r;
                    h0s[(size_t)SLOT * (i + 1) + od * 64 + b] = h_r;
                }
            }
            grid.sync();
        }
        if (tid < 256) c0g[od * 64 + b] = c_r;
    } else {
        // ----------------------------- layer 1 -----------------------------
        const int d0   = (wg - 160) * 2;
        const int didx = tid >> 6;            // owners: tid < 128
        const int od   = d0 + (didx & 1);
        float c_r = 0.f, h_r = 0.f;
        if (tid < 128) {
            c_r = c1g[od * 64 + b];
            h_r = h1s[(size_t)SLOT * TCc + od * 64 + b];
        }
        const float* wbase = Wc1 + (size_t)d0 * 5120;
        const int k0 = wv * 160;

        for (int i = 0; i <= TCc; ++i) {
            if (i > 0) {
                const float* h0p = h0s + (size_t)SLOT * i;   // h0[t0+i-1]
                const int ps = (i - 1 == 0) ? TCc : (i - 1); // h1[t0+i-2] slot
                const float* h1p = h1s + (size_t)SLOT * ps - (size_t)SLOT; // use k in [640,1280)
                const float* hsrc = (wv < 4) ? h0p : h1p;
                float acc[2][4] = {};
#pragma unroll 4
                for (int j = 0; j < 160; ++j) {
                    const int k = k0 + j;
                    const float hv = hsrc[(size_t)k * 64 + b];
#pragma unroll
                    for (int dd = 0; dd < 2; ++dd) {
                        const float4 w4 = *(const float4*)(wbase + (size_t)dd * 5120 + (size_t)k * 4);
                        acc[dd][0] = fmaf(hv, w4.x, acc[dd][0]);
                        acc[dd][1] = fmaf(hv, w4.y, acc[dd][1]);
                        acc[dd][2] = fmaf(hv, w4.z, acc[dd][2]);
                        acc[dd][3] = fmaf(hv, w4.w, acc[dd][3]);
                    }
                }
#pragma unroll
                for (int dd = 0; dd < 2; ++dd)
#pragma unroll
                    for (int g = 0; g < 4; ++g) red[dd][g][wv][b] = acc[dd][g];
                __syncthreads();
                if (tid < 128) {
                    float z[4];
#pragma unroll
                    for (int g = 0; g < 4; ++g) {
                        float s = 0.f;
#pragma unroll
                        for (int w2 = 0; w2 < 8; ++w2) s += red[didx][g][w2][b];
                        z[g] = s + b1[g * 640 + od];
                    }
                    float ig = sigm(z[0]), fg = sigm(z[1]);
                    float gg = tanhf(z[2]), og = sigm(z[3]);
                    float cn = fg * c_r + ig * gg;
                    float hn = og * tanhf(cn);
                    bool  m  = (t0 + i - 1) < len_b;
                    h_r = m ? hn : h_r;
                    c_r = m ? cn : c_r;
                    h1s[(size_t)SLOT * i + od * 64 + b] = h_r;
                }
            }
            grid.sync();
        }
        if (tid < 128) c1g[od * 64 + b] = c_r;
    }
}

// ---------------------------------------------------------------------------
// Transpose chunk: h1s slot tl+1 ([d][b]) -> out[b][t0+tl][d]
// ---------------------------------------------------------------------------
__global__ __launch_bounds__(256) void transpose_kernel(
    const float* __restrict__ h1s, float* __restrict__ out, int t0)
{
    const int tl   = blockIdx.x;
    const int dblk = blockIdx.y;
    __shared__ float tile[64][65];

    const int r  = threadIdx.x >> 2;
    const int cq = threadIdx.x & 3;

    const float* src = h1s + (size_t)SLOT * (tl + 1)
                     + (size_t)(dblk * 64 + r) * 64 + cq * 16;
#pragma unroll
    for (int j = 0; j < 4; ++j) {
        float4 vv = *(const float4*)(src + j * 4);
        tile[r][cq * 16 + j * 4 + 0] = vv.x;
        tile[r][cq * 16 + j * 4 + 1] = vv.y;
        tile[r][cq * 16 + j * 4 + 2] = vv.z;
        tile[r][cq * 16 + j * 4 + 3] = vv.w;
    }
    __syncthreads();

    float* dst = out + (size_t)r * (U_ * D_) + (size_t)(t0 + tl) * D_ + dblk * 64 + cq * 16;
#pragma unroll
    for (int j = 0; j < 4; ++j) {
        float4 ww;
        ww.x = tile[cq * 16 + j * 4 + 0][r];
        ww.y = tile[cq * 16 + j * 4 + 1][r];
        ww.z = tile[cq * 16 + j * 4 + 2][r];
        ww.w = tile[cq * 16 + j * 4 + 3][r];
        *(float4*)(dst + j * 4) = ww;
    }
}

// ---------------------------------------------------------------------------
extern "C" void kernel_launch(void* const* d_in, const int* in_sizes, int n_in,
                              void* d_out, int out_size, void* d_ws, size_t ws_size,
                              hipStream_t stream)
{
    const int*   targets = (const int*)d_in[0];
    const int*   lens    = (const int*)d_in[1];
    const float* embed   = (const float*)d_in[2];
    const float* W0      = (const float*)d_in[3];
    const float* U0      = (const float*)d_in[4];
    const float* b0      = (const float*)d_in[5];
    const float* W1      = (const float*)d_in[6];
    const float* U1      = (const float*)d_in[7];
    const float* b1      = (const float*)d_in[8];
    float* out = (float*)d_out;
    float* ws  = (float*)d_ws;

    // chunk size by workspace budget:
    // bytes(TC) = 4*(TC*163840 + (TC+1)*81920 + 4,915,200 + 81,920)
    const int TCc = (ws_size >= (size_t)83230720) ? 64 : 32;
    const int NCH = U_ / TCc;

    float* xz  = ws;                                        // TCc*2560*64
    float* W0t = xz  + (size_t)TCc * L4_ * 64;              // 1,638,400
    float* Wc1 = W0t + (size_t)640 * 640 * 4;               // 3,276,800
    float* h0s = Wc1 + (size_t)640 * 1280 * 4;              // (TCc+1)*40960
    float* h1s = h0s + (size_t)(TCc + 1) * SLOT;            // (TCc+1)*40960
    float* c0g = h1s + (size_t)(TCc + 1) * SLOT;            // 40960
    float* c1g = c0g + SLOT;                                // 40960

    // zero carry-in state (slot TCc = "h[-1]" for chunk 0) and c state
    hipMemsetAsync(h0s + (size_t)SLOT * TCc, 0, (size_t)SLOT * 4, stream);
    hipMemsetAsync(h1s + (size_t)SLOT * TCc, 0, (size_t)SLOT * 4, stream);
    hipMemsetAsync(c0g, 0, (size_t)2 * SLOT * 4, stream);

    prep_weights<<<dim3(3200), dim3(256), 0, stream>>>(U0, W1, U1, W0t, Wc1);

    for (int ch = 0; ch < NCH; ++ch) {
        const int t0 = ch * TCc;

        gemm_kernel<<<dim3(TCc * 64 / 128, L4_ / 128), dim3(256), 0, stream>>>(
            embed, targets, W0, b0, xz, t0);

        int t0v = t0, TCv = TCc;
        void* args[] = { (void*)&xz, (void*)&W0t, (void*)&Wc1, (void*)&b1,
                         (void*)&lens, (void*)&h0s, (void*)&h1s,
                         (void*)&c0g, (void*)&c1g, (void*)&t0v, (void*)&TCv };
        hipLaunchCooperativeKernel((void*)recur_chunk, dim3(RWG), dim3(512),
                                   args, 0, stream);

        transpose_kernel<<<dim3(TCc, 10), dim3(256), 0, stream>>>(h1s, out, t0);
    }
}